// Round 19
// baseline (322.896 us; speedup 1.0000x reference)
//
#include <hip/hip_runtime.h>
#include <math.h>

#define NB 8
#define NC 3
#define NN 4096
#define NK 40
#define NF 64

typedef __attribute__((ext_vector_type(8))) short bf16x8;
typedef __attribute__((ext_vector_type(4))) float floatx4;

// ---------------- cross-lane helpers (wave64) ----------------
__device__ __forceinline__ unsigned long long sx64(unsigned long long v, int m) {
  int lo = __shfl_xor((int)(unsigned)v, m, 64);
  int hi = __shfl_xor((int)(v >> 32), m, 64);
  return ((unsigned long long)(unsigned)hi << 32) | (unsigned)lo;
}

// bitonic compare-exchange on u32, descending-final network (vl = lane)
__device__ __forceinline__ void ce32k(unsigned &x, int lane, int k, int j) {
  unsigned o = (unsigned)__shfl_xor((int)x, j, 64);
  const bool tm = ((lane & j) == 0) == ((lane & k) == 0);
  const unsigned mx = x > o ? x : o;
  const unsigned mn = x > o ? o : x;
  x = tm ? mx : mn;
}
__device__ __forceinline__ void sort64_u32(unsigned &x, int lane) {
  #pragma unroll
  for (int k = 2; k <= 64; k <<= 1) {
    #pragma unroll
    for (int j = k >> 1; j >= 1; j >>= 1) ce32k(x, lane, k, j);
  }
}
__device__ __forceinline__ void merge64_u32(unsigned &a, unsigned b, int lane) {
  unsigned br = (unsigned)__shfl((int)b, 63 - lane, 64);   // reverse -> ascending
  a = a > br ? a : br;                                     // half-cleaner: keep maxes
  #pragma unroll
  for (int j = 32; j >= 1; j >>= 1) {
    unsigned o = (unsigned)__shfl_xor((int)a, j, 64);
    const bool tm = (lane & j) == 0;
    const unsigned mx = a > o ? a : o;
    const unsigned mn = a > o ? o : a;
    a = tm ? mx : mn;
  }
}
__device__ __forceinline__ void ce64k(unsigned long long &x, int lane, int k, int j) {
  unsigned long long o = sx64(x, j);
  const bool tm = ((lane & j) == 0) == ((lane & k) == 0);
  const unsigned long long mx = x > o ? x : o;
  const unsigned long long mn = x > o ? o : x;
  x = tm ? mx : mn;
}
__device__ __forceinline__ void sort64_u64(unsigned long long &x, int lane) {
  #pragma unroll
  for (int k = 2; k <= 64; k <<= 1) {
    #pragma unroll
    for (int j = k >> 1; j >= 1; j >>= 1) ce64k(x, lane, k, j);
  }
}

// order-preserving float <-> uint (all floats): ascending float = ascending uint
__device__ __forceinline__ unsigned encf(float f) {
  unsigned u = __float_as_uint(f);
  return u ^ ((unsigned)((int)u >> 31) | 0x80000000u);
}
__device__ __forceinline__ float decf(unsigned e) {
  unsigned u = (e & 0x80000000u) ? (e ^ 0x80000000u) : ~e;
  return __uint_as_float(u);
}

// float -> bf16 bits, round-to-nearest-even (finite inputs only)
__device__ __forceinline__ unsigned short f2bf(float x) {
  unsigned u = __float_as_uint(x);
  u = (u + 0x7FFFu + ((u >> 16) & 1u)) >> 16;
  return (unsigned short)u;
}
// 16-lane-group reductions (xor masks < 16 stay within the lane/16 group)
__device__ __forceinline__ float red16max(float v) {
  v = fmaxf(v, __shfl_xor(v, 1, 64));
  v = fmaxf(v, __shfl_xor(v, 2, 64));
  v = fmaxf(v, __shfl_xor(v, 4, 64));
  v = fmaxf(v, __shfl_xor(v, 8, 64));
  return v;
}
__device__ __forceinline__ float red16min(float v) {
  v = fminf(v, __shfl_xor(v, 1, 64));
  v = fminf(v, __shfl_xor(v, 2, 64));
  v = fminf(v, __shfl_xor(v, 4, 64));
  v = fminf(v, __shfl_xor(v, 8, 64));
  return v;
}
__device__ __forceinline__ float red16sum(float v) {
  v += __shfl_xor(v, 1, 64);
  v += __shfl_xor(v, 2, 64);
  v += __shfl_xor(v, 4, 64);
  v += __shfl_xor(v, 8, 64);
  return v;
}

// ---------------- k0: build xyzs = (x,y,z,|p|^2) ----------------
__global__ __launch_bounds__(256) void k0_prep(const float* __restrict__ x, float4* __restrict__ xyzs) {
  const int i = blockIdx.x * 256 + threadIdx.x;   // 0..32767
  const int b = i >> 12, n = i & 4095;
  const float* xb = x + b * (NC * NN);
  const float a0 = xb[n], a1 = xb[n + NN], a2 = xb[n + 2 * NN];
  const float sq = fmaf(a2, a2, fmaf(a1, a1, a0 * a0));
  xyzs[i] = make_float4(a0, a1, a2, sq);
}

// ---------------- k1: exact KNN top-40, 3-FMA expanded screen + f64 re-rank ----------
// 1024-thread blocks: 16 waves share ONE point tile (split float2 arrays), 4 q/wave.
// screen value v = |p|^2 - 2 q.p ; running threshold = 40th-best (exact superset of
// true top-40 via monotone quantized-bucket compare). LDS 32+32+16 = 80 KB, 2 blk/CU.
__global__ __launch_bounds__(1024) void k1_knn(const float4* __restrict__ xyzs, int* __restrict__ idxo) {
  __shared__ float2 xy2[NN];             // 32 KB (x,y)
  __shared__ float2 zw2[NN];             // 32 KB (z,|p|^2)
  __shared__ unsigned kq[16][4][64];     // 16 KB: [wave][query][slot]
  const int tid = threadIdx.x;
  const int b = blockIdx.x >> 6;
  const int blkq = blockIdx.x & 63;
  const int w = tid >> 6, lane = tid & 63;
  for (int i = tid; i < NN; i += 1024) {
    const float4 v = xyzs[b * NN + i];
    xy2[i] = make_float2(v.x, v.y);
    zw2[i] = make_float2(v.z, v.w);
  }
  __syncthreads();
  const unsigned long long lmask = (1ull << lane) - 1ull;

  const int q0 = blkq * 64 + w * 4;     // queries q0..q0+3
  float m2x[4], m2y[4], m2z[4], thrF[4];
  unsigned a_[4];
  int cnt[4];
  #pragma unroll
  for (int j = 0; j < 4; ++j) {
    const float2 t = xy2[q0 + j];
    m2x[j] = -2.f * t.x; m2y[j] = -2.f * t.y; m2z[j] = -2.f * zw2[q0 + j].x;
    a_[j] = 0u;
    thrF[j] = __uint_as_float(0x7F800000u);      // +inf: everything passes initially
    cnt[j] = 0;
  }

  // software-pipelined candidate stream: prefetch step m0+64 while processing m0
  float2 pxy = xy2[lane];
  float2 pzw = zw2[lane];
  #pragma unroll 1
  for (int m0 = 0; m0 < NN; m0 += 64) {
    const float2 cxy = pxy;
    const float2 czw = pzw;
    if (m0 + 64 < NN) {
      pxy = xy2[m0 + 64 + lane];
      pzw = zw2[m0 + 64 + lane];
    }
    const unsigned idxbits = (unsigned)(4095 - (m0 + lane));
    #pragma unroll
    for (int j = 0; j < 4; ++j) {
      const float v = fmaf(m2x[j], cxy.x, fmaf(m2y[j], cxy.y, fmaf(m2z[j], czw.x, czw.y)));
      const bool cand = v < thrF[j];             // 1-op screen
      const unsigned long long bal = __ballot(cand);
      if (bal) {
        const int npass = __popcll(bal);
        if (cnt[j] + npass > 64) {               // merge BEFORE insert; cnt<=64 entries
          unsigned bb = (lane < cnt[j]) ? kq[w][j][lane] : 0u;
          sort64_u32(bb, lane);
          merge64_u32(a_[j], bb, lane);
          cnt[j] = 0;
          const unsigned thr_key = (unsigned)__shfl((int)a_[j], 39, 64);  // 40th best
          // pass iff quantized enc(v) <= quantized enc of 40th (exact top-40 superset)
          thrF[j] = decf((~thr_key & 0xFFFFF000u) + 0x1000u);
        }
        const int rank = __popcll(bal & lmask);
        if (cand) {
          kq[w][j][cnt[j] + rank] = (~encf(v) & 0xFFFFF000u) | idxbits;
        }
        cnt[j] += npass;
      }
    }
  }
  // drain + exact f64 re-rank per query
  #pragma unroll 1
  for (int j = 0; j < 4; ++j) {
    if (cnt[j] > 0) {
      unsigned bb = (lane < cnt[j]) ? kq[w][j][lane] : 0u;
      sort64_u32(bb, lane);
      merge64_u32(a_[j], bb, lane);
    }
    const int m = 4095 - (int)(a_[j] & 0xFFFu);
    const float2 pxy_ = xy2[m];
    const float pz_ = zw2[m].x;
    const float2 qxy_ = xy2[q0 + j];
    const float qz_ = zw2[q0 + j].x;
    const double dx = (double)qxy_.x - (double)pxy_.x;
    const double dy = (double)qxy_.y - (double)pxy_.y;
    const double dz = (double)qz_ - (double)pz_;
    const double d2d = fma(dx, dx, fma(dy, dy, dz * dz));
    const float pd = (float)(-d2d);                 // single rounding from exact
    unsigned u = __float_as_uint(pd);
    u ^= (unsigned)((int)u >> 31) | 0x80000000u;    // order-preserving float->uint
    unsigned long long key = ((unsigned long long)u << 32) | (unsigned)(4095 - m);
    sort64_u64(key, lane);
    if (lane < NK) idxo[(b * NN + q0 + j) * NK + lane] = 4095 - (int)(key & 0xFFFFFFFFull);
  }
}

// ---------------- k2: edge-feature moments (6 sums + 21 upper-tri products) ----------------
__global__ __launch_bounds__(256) void k2_mom(const float4* __restrict__ xyzs, const int* __restrict__ idx,
                                              float* __restrict__ part) {
  const int tid = threadIdx.x;
  const int gid = blockIdx.x * 256 + tid;
  float acc[27];
  #pragma unroll
  for (int j = 0; j < 27; ++j) acc[j] = 0.f;
  for (int i = 0; i < 10; ++i) {
    const int s = gid + i * 131072;          // B*N*K = 1310720 = 131072*10
    const int b = s / 163840;                // N*K
    const int r = s - b * 163840;
    const int n = r / 40;
    const int m = idx[s];
    const float4 ct = xyzs[b * NN + n];
    const float4 nb = xyzs[b * NN + m];
    const float e[6] = {nb.x - ct.x, nb.y - ct.y, nb.z - ct.z, ct.x, ct.y, ct.z};
    int t = 6;
    #pragma unroll
    for (int c = 0; c < 6; ++c) {
      acc[c] += e[c];
      #pragma unroll
      for (int d = c; d < 6; ++d) { acc[t] = fmaf(e[c], e[d], acc[t]); ++t; }
    }
  }
  const int w = tid >> 6, lane = tid & 63;
  __shared__ float red[4][27];
  #pragma unroll
  for (int j = 0; j < 27; ++j) {
    float v = acc[j];
    #pragma unroll
    for (int mm = 1; mm < 64; mm <<= 1) v += __shfl_xor(v, mm, 64);
    if (lane == 0) red[w][j] = v;
  }
  __syncthreads();
  if (tid < 27) part[blockIdx.x * 27 + tid] = red[0][tid] + red[1][tid] + red[2][tid] + red[3][tid];
}

// ---------------- k3: BN1 stats (analytic from moments), fold into W1 ----------------
__global__ void k3_stats1(const float* __restrict__ part, const float* __restrict__ W1,
                          const float* __restrict__ g1, const float* __restrict__ b1,
                          float* __restrict__ s1) {
  __shared__ float S[27];
  const int t = threadIdx.x;
  if (t < 27) {
    double s = 0.0;
    for (int p = 0; p < 512; ++p) s += (double)part[p * 27 + t];
    S[t] = (float)s;
  }
  __syncthreads();
  if (t < 64) {
    const float inv = 1.f / 1310720.f;
    float mu[6];
    #pragma unroll
    for (int c = 0; c < 6; ++c) mu[c] = S[c] * inv;
    float M[6][6];
    int tt = 6;
    #pragma unroll
    for (int c = 0; c < 6; ++c) {
      #pragma unroll
      for (int d = c; d < 6; ++d) { const float v = S[tt] * inv; M[c][d] = v; M[d][c] = v; ++tt; }
    }
    float wv[6];
    #pragma unroll
    for (int c = 0; c < 6; ++c) wv[c] = W1[t * 6 + c];
    float mean = 0.f;
    #pragma unroll
    for (int c = 0; c < 6; ++c) mean = fmaf(wv[c], mu[c], mean);
    float e2 = 0.f;
    #pragma unroll
    for (int c = 0; c < 6; ++c) {
      float rowdot = 0.f;
      #pragma unroll
      for (int d = 0; d < 6; ++d) rowdot = fmaf(wv[d], M[c][d], rowdot);
      e2 = fmaf(wv[c], rowdot, e2);
    }
    const float var = e2 - mean * mean;
    const float aa = g1[t] / sqrtf(var + 1e-5f);
    const float cc = b1[t] - mean * aa;
    #pragma unroll
    for (int c = 0; c < 6; ++c) s1[t * 8 + c] = aa * wv[c];  // pre-folded W1' = a1*W1
    s1[t * 8 + 6] = cc;
    s1[t * 8 + 7] = 0.f;
  }
}

// ---------------- k46: W2 stage on MFMA (bf16 16x16x32), tile-pipelined, reg-neighbors --
// wave = 2 points = 80 samples = 5 column-tiles of 16 (no padding).
// All 80 neighbor coords are loaded ONCE via per-lane vector loads (vmcnt path):
// lane l holds neighbor l of point A and of point B. z-gen uses compile-time-lane
// __shfl broadcasts -> ZERO memory ops in the k-loop (no lgkm s_load/ds entanglement).
// Pipeline: read B-frags(t) -> z-gen(t+1) into other zlds buffer -> MFMA+stats(t).
// C layout (verified m89): col=lane&15, row=(lane>>4)*4+reg. A: row=lane%16,
// k=(lane/16)*8+j. B: col=lane%16, k=(lane/16)*8+j.
// MODE 0: stats + raw-y2 max/min; MODE 1: stats only; MODE 2: final using s2.
template<int MODE>
__global__ __launch_bounds__(256) void k46(const float4* __restrict__ xyzs, const int* __restrict__ idx,
                                           const float* __restrict__ s1, const float* __restrict__ W2,
                                           const float* __restrict__ s2, float* __restrict__ part,
                                           float* __restrict__ ymax, float* __restrict__ ymin,
                                           float* __restrict__ out) {
  __shared__ bf16x8 w2f[8][64];                   // A-fragments [ft*2+kh][lane], 8 KB
  __shared__ unsigned short zlds[4][2][16][64];   // [wave][dbuf][col][g], 16 KB
  __shared__ float red[4][128];                   // 2 KB
  const int tid = threadIdx.x, w = tid >> 6, lane = tid & 63;
  const int G = lane >> 4, l16 = lane & 15;

  // stage W2 -> bf16 A-fragments: chunk = (ftkh, L): value j = W2[ft*16 + L%16][kh*32 + (L/16)*8 + j]
  {
    #pragma unroll
    for (int i = 0; i < 2; ++i) {
      const int chunk = tid * 2 + i;
      const int ftkh = chunk >> 6, L = chunk & 63;
      const int f = (ftkh >> 1) * 16 + (L & 15);
      const int g0 = (ftkh & 1) * 32 + (L >> 4) * 8;
      const float4 wa = *(const float4*)(W2 + f * 64 + g0);
      const float4 wb = *(const float4*)(W2 + f * 64 + g0 + 4);
      bf16x8 v;
      v[0] = (short)f2bf(wa.x); v[1] = (short)f2bf(wa.y);
      v[2] = (short)f2bf(wa.z); v[3] = (short)f2bf(wa.w);
      v[4] = (short)f2bf(wb.x); v[5] = (short)f2bf(wb.y);
      v[6] = (short)f2bf(wb.z); v[7] = (short)f2bf(wb.w);
      w2f[ftkh][L] = v;
    }
  }
  __syncthreads();

  const int pA = blockIdx.x * 8 + w * 2;     // two consecutive points per wave
  const int pB = pA + 1;
  const int pbse = pA & ~(NN - 1);           // b*NN
  // per-lane s1 row (lane = feature g); center term folded into zb (ct dead in loop)
  const float4 s1v0 = ((const float4*)(s1 + lane * 8))[0];   // w0,w1,w2,w3
  const float4 s1v1 = ((const float4*)(s1 + lane * 8))[1];   // w4,w5,cc,pad
  const float s1x = s1v0.x, s1y = s1v0.y, s1z = s1v0.z;
  float zbA, zbB;
  {
    const float4 ctA = xyzs[pA];
    const float4 ctB = xyzs[pB];
    float z = s1v1.z;
    z = fmaf(s1v0.w, ctA.x, z);
    z = fmaf(s1v1.x, ctA.y, z);
    z = fmaf(s1v1.y, ctA.z, z);
    z = fmaf(-s1x, ctA.x, z);
    z = fmaf(-s1y, ctA.y, z);
    z = fmaf(-s1z, ctA.z, z);
    zbA = z;
    z = s1v1.z;
    z = fmaf(s1v0.w, ctB.x, z);
    z = fmaf(s1v1.x, ctB.y, z);
    z = fmaf(s1v1.y, ctB.z, z);
    z = fmaf(-s1x, ctB.x, z);
    z = fmaf(-s1y, ctB.y, z);
    z = fmaf(-s1z, ctB.z, z);
    zbB = z;
  }
  __shared__ float s2l[128];
  if (MODE == 2 && tid < 128) s2l[tid] = s2[tid];
  if (MODE == 2) __syncthreads();

  // per-lane neighbor coords: lane l holds neighbor l of A and of B (vector loads)
  const int ia0 = (lane < NK) ? idx[pA * NK + lane] : 0;
  const int ia1 = (lane < NK) ? idx[pB * NK + lane] : 0;
  const float4 nA4 = xyzs[pbse + ia0];
  const float4 nB4 = xyzs[pbse + ia1];
  const float nAx = nA4.x, nAy = nA4.y, nAz = nA4.z;
  const float nBx = nB4.x, nBy = nB4.y, nBz = nB4.z;
  unsigned short* zw = &zlds[w][0][0][0];

  // z-gen for tile TT into buffer BUF: pure VALU + ds_write (shfl from const lanes)
  #define K46_ZGEN(TT, BUF)                                             \
  {                                                                     \
    _Pragma("unroll")                                                   \
    for (int c = 0; c < 16; ++c) {                                      \
      const int sidx = (TT) * 16 + c;                                   \
      const int pt = sidx / NK;                                         \
      const int kk = sidx % NK;                                         \
      const float nx = __shfl(pt ? nBx : nAx, kk, 64);                  \
      const float ny = __shfl(pt ? nBy : nAy, kk, 64);                  \
      const float nz = __shfl(pt ? nBz : nAz, kk, 64);                  \
      float z = pt ? zbB : zbA;                                         \
      z = fmaf(s1x, nx, z);                                             \
      z = fmaf(s1y, ny, z);                                             \
      z = fmaf(s1z, nz, z);                                             \
      z = fmaxf(z, 0.2f * z);                                           \
      zw[(BUF) * 1024 + c * 64 + lane] = f2bf(z);                       \
    }                                                                   \
  }

  float s_[4][4], q_[4][4], mx_[4][4], mn_[4][4];
  #pragma unroll
  for (int ft = 0; ft < 4; ++ft)
    #pragma unroll
    for (int r = 0; r < 4; ++r) {
      s_[ft][r] = 0.f; q_[ft][r] = 0.f; mx_[ft][r] = -3.0e38f; mn_[ft][r] = 3.0e38f;
    }

  // prologue: z-gen tile 0 -> buffer 0
  K46_ZGEN(0, 0)

  #pragma unroll
  for (int t = 0; t < 5; ++t) {
    // (1) B-fragments of tile t (written last iteration; drained during its stats)
    const int bo = (t & 1) * 1024;
    const bf16x8 bf0 = *(const bf16x8*)(zw + bo + l16 * 64 + G * 8);
    const bf16x8 bf1 = *(const bf16x8*)(zw + bo + l16 * 64 + 32 + G * 8);
    // (2) z-gen tile t+1 into the other buffer (hides bf read latency)
    if (t < 4) K46_ZGEN(t + 1, (t + 1) & 1)
    // (3) MFMA + stats of tile t
    #pragma unroll
    for (int ft = 0; ft < 4; ++ft) {
      floatx4 acc = {0.f, 0.f, 0.f, 0.f};
      acc = __builtin_amdgcn_mfma_f32_16x16x32_bf16(w2f[ft * 2 + 0][lane], bf0, acc, 0, 0, 0);
      acc = __builtin_amdgcn_mfma_f32_16x16x32_bf16(w2f[ft * 2 + 1][lane], bf1, acc, 0, 0, 0);
      #pragma unroll
      for (int r = 0; r < 4; ++r) {
        const float y = acc[r];
        if (MODE != 2) { s_[ft][r] += y; q_[ft][r] = fmaf(y, y, q_[ft][r]); }
        float v = y;
        if (MODE == 2) {
          const int fown = ft * 16 + G * 4 + r;   // f of THIS value (row of C)
          const float tv = fmaf(y, s2l[2 * fown], s2l[2 * fown + 1]);
          v = fmaxf(tv, 0.2f * tv);
        }
        if (MODE != 1) {
          if (t == 0 || t == 1 || t == 3) {
            mx_[ft][r] = fmaxf(mx_[ft][r], v);
            if (MODE == 0) mn_[ft][r] = fminf(mn_[ft][r], v);
          } else if (t == 2) {
            // close out point A for this (ft,r): cols 0-7 of this tile belong to A
            float fx = (l16 < 8) ? fmaxf(mx_[ft][r], v) : mx_[ft][r];
            fx = red16max(fx);
            float fn = 3.0e38f;
            if (MODE == 0) {
              fn = (l16 < 8) ? fminf(mn_[ft][r], v) : mn_[ft][r];
              fn = red16min(fn);
            }
            if (l16 == ft * 4 + r) {
              const int f = ft * 16 + G * 4 + r;
              if (MODE == 0) { ymax[pA * NF + f] = fx; ymin[pA * NF + f] = fn; }
              else { out[pbse * NF + f * NN + (pA & (NN - 1))] = fx; }
            }
            mx_[ft][r] = (l16 >= 8) ? v : -3.0e38f;     // start point B
            if (MODE == 0) mn_[ft][r] = (l16 >= 8) ? v : 3.0e38f;
          } else { // t == 4: update + close out point B
            float fx = fmaxf(mx_[ft][r], v);
            fx = red16max(fx);
            float fn = 3.0e38f;
            if (MODE == 0) {
              fn = fminf(mn_[ft][r], v);
              fn = red16min(fn);
            }
            if (l16 == ft * 4 + r) {
              const int f = ft * 16 + G * 4 + r;
              if (MODE == 0) { ymax[pB * NF + f] = fx; ymin[pB * NF + f] = fn; }
              else { out[pbse * NF + f * NN + (pB & (NN - 1))] = fx; }
            }
          }
        }
      }
    }
  }
  #undef K46_ZGEN

  if (MODE != 2) {
    // wave-end: reduce deferred sums over the 16 columns-lanes, owner writes red[w][f]
    #pragma unroll
    for (int ft = 0; ft < 4; ++ft) {
      #pragma unroll
      for (int r = 0; r < 4; ++r) {
        const float ss = red16sum(s_[ft][r]);
        const float qq = red16sum(q_[ft][r]);
        if (l16 == ft * 4 + r) {
          const int f = ft * 16 + G * 4 + r;
          red[w][f] = ss;
          red[w][64 + f] = qq;
        }
      }
    }
    __syncthreads();
    if (tid < 128) part[blockIdx.x * 128 + tid] = red[0][tid] + red[1][tid] + red[2][tid] + red[3][tid];
  }
}

// ---------------- k5a: reduce BN2 partials (4096 x 128) -> sums[128] ----------------
__global__ __launch_bounds__(256) void k5a(const float* __restrict__ part, float* __restrict__ sums) {
  const int t = blockIdx.x;         // stat index 0..127
  const int tid = threadIdx.x;
  double s = 0.0;
  for (int p = tid; p < 4096; p += 256) s += (double)part[p * 128 + t];
  __shared__ double sd[256];
  sd[tid] = s;
  __syncthreads();
  for (int st = 128; st > 0; st >>= 1) {
    if (tid < st) sd[tid] += sd[tid + st];
    __syncthreads();
  }
  if (tid == 0) sums[t] = (float)sd[0];
}

// ---------------- k5b: sums -> affine (a2, c2) ----------------
__global__ void k5b(const float* __restrict__ sums, const float* __restrict__ g2,
                    const float* __restrict__ b2, float* __restrict__ s2) {
  const int t = threadIdx.x;  // 64
  const float inv = 1.f / 1310720.f;
  const float mean = sums[t] * inv;
  const float var = sums[t + 64] * inv - mean * mean;
  const float aa = g2[t] / sqrtf(var + 1e-5f);
  s2[2 * t] = aa;
  s2[2 * t + 1] = b2[t] - mean * aa;
}

// ---------------- k7: affine+lrelu on proper extreme, with LDS tile transpose ----------------
// max_k lrelu(a*y+c) == lrelu(a*max_k y + c) if a>=0 else lrelu(a*min_k y + c)
__global__ __launch_bounds__(256) void k7_apply(const float* __restrict__ ymax, const float* __restrict__ ymin,
                                                const float* __restrict__ s2, float* __restrict__ out) {
  __shared__ float tile[64][65];
  const int blk = blockIdx.x;                 // 0..511
  const int b = blk >> 6, n0 = (blk & 63) * 64;
  const int tid = threadIdx.x;
  const int fr = tid & 63;
  const float aa = s2[2 * fr], cc = s2[2 * fr + 1];
  const bool useMax = (aa >= 0.f);
  #pragma unroll
  for (int it = 0; it < 16; ++it) {
    const int nl = it * 4 + (tid >> 6);
    const int gi = ((b * NN + n0 + nl) << 6) + fr;     // [point][f]
    const float v = useMax ? ymax[gi] : ymin[gi];
    const float t0 = fmaf(aa, v, cc);
    tile[fr][nl] = fmaxf(t0, 0.2f * t0);
  }
  __syncthreads();
  #pragma unroll
  for (int it = 0; it < 16; ++it) {
    const int fw = it * 4 + (tid >> 6);
    const int nl = tid & 63;
    out[(b * NF + fw) * NN + n0 + nl] = tile[fw][nl];  // coalesced
  }
}

extern "C" void kernel_launch(void* const* d_in, const int* in_sizes, int n_in,
                              void* d_out, int out_size, void* d_ws, size_t ws_size,
                              hipStream_t stream) {
  const float* x  = (const float*)d_in[0];
  const float* W1 = (const float*)d_in[1];
  const float* g1 = (const float*)d_in[2];
  const float* b1 = (const float*)d_in[3];
  const float* W2 = (const float*)d_in[4];
  const float* g2 = (const float*)d_in[5];
  const float* b2 = (const float*)d_in[6];
  float* out = (float*)d_out;
  char* ws = (char*)d_ws;
  // workspace layout (16B-aligned slabs)
  float4* xyzs  = (float4*)ws;                       // 524288 B
  int*    idx   = (int*)(ws + 524288);               // 5242880 B -> end 5767168
  float*  part2 = (float*)(ws + 5767168);            // 55296 B   -> end 5822464
  float*  s1    = (float*)(ws + 5822464);            // 2048 B    -> end 5824512
  float*  part4 = (float*)(ws + 5824512);            // 2097152 B -> end 10018816 (slab kept)
  float*  sums  = (float*)(ws + 10018816);           // 512 B     -> end 10019328
  float*  s2    = (float*)(ws + 10019328);           // 512 B     -> end 10019840
  float*  ymax  = (float*)(ws + 10019840);           // 8388608 B -> end 18408448
  float*  ymin  = (float*)(ws + 18408448);           // 8388608 B -> end 26797056
  const size_t FUSED_NEED = 26797056;                // bytes

  k0_prep<<<128, 256, 0, stream>>>(x, xyzs);
  k1_knn<<<512, 1024, 0, stream>>>(xyzs, idx);
  k2_mom<<<512, 256, 0, stream>>>(xyzs, idx, part2);
  k3_stats1<<<1, 64, 0, stream>>>(part2, W1, g1, b1, s1);
  if (ws_size >= FUSED_NEED) {
    k46<0><<<4096, 256, 0, stream>>>(xyzs, idx, s1, W2, s2, part4, ymax, ymin, out);
    k5a<<<128, 256, 0, stream>>>(part4, sums);
    k5b<<<1, 64, 0, stream>>>(sums, g2, b2, s2);
    k7_apply<<<512, 256, 0, stream>>>(ymax, ymin, s2, out);
  } else {
    k46<1><<<4096, 256, 0, stream>>>(xyzs, idx, s1, W2, s2, part4, out, out, out);
    k5a<<<128, 256, 0, stream>>>(part4, sums);
    k5b<<<1, 64, 0, stream>>>(sums, g2, b2, s2);
    k46<2><<<4096, 256, 0, stream>>>(xyzs, idx, s1, W2, s2, part4, out, out, out);
  }
}

// Round 20
// 298.764 us; speedup vs baseline: 1.0808x; 1.0808x over previous
//
#include <hip/hip_runtime.h>
#include <math.h>

#define NB 8
#define NC 3
#define NN 4096
#define NK 40
#define NF 64

typedef __attribute__((ext_vector_type(8))) short bf16x8;
typedef __attribute__((ext_vector_type(4))) float floatx4;

// ---------------- cross-lane helpers (wave64) ----------------
__device__ __forceinline__ unsigned long long sx64(unsigned long long v, int m) {
  int lo = __shfl_xor((int)(unsigned)v, m, 64);
  int hi = __shfl_xor((int)(v >> 32), m, 64);
  return ((unsigned long long)(unsigned)hi << 32) | (unsigned)lo;
}

// bitonic compare-exchange on u32, descending-final network (vl = lane)
__device__ __forceinline__ void ce32k(unsigned &x, int lane, int k, int j) {
  unsigned o = (unsigned)__shfl_xor((int)x, j, 64);
  const bool tm = ((lane & j) == 0) == ((lane & k) == 0);
  const unsigned mx = x > o ? x : o;
  const unsigned mn = x > o ? o : x;
  x = tm ? mx : mn;
}
__device__ __forceinline__ void sort64_u32(unsigned &x, int lane) {
  #pragma unroll
  for (int k = 2; k <= 64; k <<= 1) {
    #pragma unroll
    for (int j = k >> 1; j >= 1; j >>= 1) ce32k(x, lane, k, j);
  }
}
__device__ __forceinline__ void merge64_u32(unsigned &a, unsigned b, int lane) {
  unsigned br = (unsigned)__shfl((int)b, 63 - lane, 64);   // reverse -> ascending
  a = a > br ? a : br;                                     // half-cleaner: keep maxes
  #pragma unroll
  for (int j = 32; j >= 1; j >>= 1) {
    unsigned o = (unsigned)__shfl_xor((int)a, j, 64);
    const bool tm = (lane & j) == 0;
    const unsigned mx = a > o ? a : o;
    const unsigned mn = a > o ? o : a;
    a = tm ? mx : mn;
  }
}
__device__ __forceinline__ void ce64k(unsigned long long &x, int lane, int k, int j) {
  unsigned long long o = sx64(x, j);
  const bool tm = ((lane & j) == 0) == ((lane & k) == 0);
  const unsigned long long mx = x > o ? x : o;
  const unsigned long long mn = x > o ? o : x;
  x = tm ? mx : mn;
}
__device__ __forceinline__ void sort64_u64(unsigned long long &x, int lane) {
  #pragma unroll
  for (int k = 2; k <= 64; k <<= 1) {
    #pragma unroll
    for (int j = k >> 1; j >= 1; j >>= 1) ce64k(x, lane, k, j);
  }
}

// order-preserving float <-> uint (all floats): ascending float = ascending uint
__device__ __forceinline__ unsigned encf(float f) {
  unsigned u = __float_as_uint(f);
  return u ^ ((unsigned)((int)u >> 31) | 0x80000000u);
}
__device__ __forceinline__ float decf(unsigned e) {
  unsigned u = (e & 0x80000000u) ? (e ^ 0x80000000u) : ~e;
  return __uint_as_float(u);
}

// float -> bf16 bits, round-to-nearest-even (finite inputs only)
__device__ __forceinline__ unsigned short f2bf(float x) {
  unsigned u = __float_as_uint(x);
  u = (u + 0x7FFFu + ((u >> 16) & 1u)) >> 16;
  return (unsigned short)u;
}
// 16-lane-group reductions (xor masks < 16 stay within the lane/16 group)
__device__ __forceinline__ float red16max(float v) {
  v = fmaxf(v, __shfl_xor(v, 1, 64));
  v = fmaxf(v, __shfl_xor(v, 2, 64));
  v = fmaxf(v, __shfl_xor(v, 4, 64));
  v = fmaxf(v, __shfl_xor(v, 8, 64));
  return v;
}
__device__ __forceinline__ float red16min(float v) {
  v = fminf(v, __shfl_xor(v, 1, 64));
  v = fminf(v, __shfl_xor(v, 2, 64));
  v = fminf(v, __shfl_xor(v, 4, 64));
  v = fminf(v, __shfl_xor(v, 8, 64));
  return v;
}
__device__ __forceinline__ float red16sum(float v) {
  v += __shfl_xor(v, 1, 64);
  v += __shfl_xor(v, 2, 64);
  v += __shfl_xor(v, 4, 64);
  v += __shfl_xor(v, 8, 64);
  return v;
}

// ---------------- k0: build xyzs = (x,y,z,|p|^2) ----------------
__global__ __launch_bounds__(256) void k0_prep(const float* __restrict__ x, float4* __restrict__ xyzs) {
  const int i = blockIdx.x * 256 + threadIdx.x;   // 0..32767
  const int b = i >> 12, n = i & 4095;
  const float* xb = x + b * (NC * NN);
  const float a0 = xb[n], a1 = xb[n + NN], a2 = xb[n + 2 * NN];
  const float sq = fmaf(a2, a2, fmaf(a1, a1, a0 * a0));
  xyzs[i] = make_float4(a0, a1, a2, sq);
}

// ---------------- k1: exact KNN top-40, 3-FMA expanded screen + f64 re-rank ----------
// 1024-thread blocks: 16 waves share ONE point tile (split float2 arrays), 4 q/wave.
// screen value v = |p|^2 - 2 q.p ; running threshold = 40th-best (exact superset of
// true top-40 via monotone quantized-bucket compare). LDS 32+32+16 = 80 KB, 2 blk/CU.
__global__ __launch_bounds__(1024) void k1_knn(const float4* __restrict__ xyzs, int* __restrict__ idxo) {
  __shared__ float2 xy2[NN];             // 32 KB (x,y)
  __shared__ float2 zw2[NN];             // 32 KB (z,|p|^2)
  __shared__ unsigned kq[16][4][64];     // 16 KB: [wave][query][slot]
  const int tid = threadIdx.x;
  const int b = blockIdx.x >> 6;
  const int blkq = blockIdx.x & 63;
  const int w = tid >> 6, lane = tid & 63;
  for (int i = tid; i < NN; i += 1024) {
    const float4 v = xyzs[b * NN + i];
    xy2[i] = make_float2(v.x, v.y);
    zw2[i] = make_float2(v.z, v.w);
  }
  __syncthreads();
  const unsigned long long lmask = (1ull << lane) - 1ull;

  const int q0 = blkq * 64 + w * 4;     // queries q0..q0+3
  float m2x[4], m2y[4], m2z[4], thrF[4];
  unsigned a_[4];
  int cnt[4];
  #pragma unroll
  for (int j = 0; j < 4; ++j) {
    const float2 t = xy2[q0 + j];
    m2x[j] = -2.f * t.x; m2y[j] = -2.f * t.y; m2z[j] = -2.f * zw2[q0 + j].x;
    a_[j] = 0u;
    thrF[j] = __uint_as_float(0x7F800000u);      // +inf: everything passes initially
    cnt[j] = 0;
  }

  // software-pipelined candidate stream: prefetch step m0+64 while processing m0
  float2 pxy = xy2[lane];
  float2 pzw = zw2[lane];
  #pragma unroll 1
  for (int m0 = 0; m0 < NN; m0 += 64) {
    const float2 cxy = pxy;
    const float2 czw = pzw;
    if (m0 + 64 < NN) {
      pxy = xy2[m0 + 64 + lane];
      pzw = zw2[m0 + 64 + lane];
    }
    const unsigned idxbits = (unsigned)(4095 - (m0 + lane));
    #pragma unroll
    for (int j = 0; j < 4; ++j) {
      const float v = fmaf(m2x[j], cxy.x, fmaf(m2y[j], cxy.y, fmaf(m2z[j], czw.x, czw.y)));
      const bool cand = v < thrF[j];             // 1-op screen
      const unsigned long long bal = __ballot(cand);
      if (bal) {
        const int npass = __popcll(bal);
        if (cnt[j] + npass > 64) {               // merge BEFORE insert; cnt<=64 entries
          unsigned bb = (lane < cnt[j]) ? kq[w][j][lane] : 0u;
          sort64_u32(bb, lane);
          merge64_u32(a_[j], bb, lane);
          cnt[j] = 0;
          const unsigned thr_key = (unsigned)__shfl((int)a_[j], 39, 64);  // 40th best
          // pass iff quantized enc(v) <= quantized enc of 40th (exact top-40 superset)
          thrF[j] = decf((~thr_key & 0xFFFFF000u) + 0x1000u);
        }
        const int rank = __popcll(bal & lmask);
        if (cand) {
          kq[w][j][cnt[j] + rank] = (~encf(v) & 0xFFFFF000u) | idxbits;
        }
        cnt[j] += npass;
      }
    }
  }
  // drain + exact f64 re-rank per query
  #pragma unroll 1
  for (int j = 0; j < 4; ++j) {
    if (cnt[j] > 0) {
      unsigned bb = (lane < cnt[j]) ? kq[w][j][lane] : 0u;
      sort64_u32(bb, lane);
      merge64_u32(a_[j], bb, lane);
    }
    const int m = 4095 - (int)(a_[j] & 0xFFFu);
    const float2 pxy_ = xy2[m];
    const float pz_ = zw2[m].x;
    const float2 qxy_ = xy2[q0 + j];
    const float qz_ = zw2[q0 + j].x;
    const double dx = (double)qxy_.x - (double)pxy_.x;
    const double dy = (double)qxy_.y - (double)pxy_.y;
    const double dz = (double)qz_ - (double)pz_;
    const double d2d = fma(dx, dx, fma(dy, dy, dz * dz));
    const float pd = (float)(-d2d);                 // single rounding from exact
    unsigned u = __float_as_uint(pd);
    u ^= (unsigned)((int)u >> 31) | 0x80000000u;    // order-preserving float->uint
    unsigned long long key = ((unsigned long long)u << 32) | (unsigned)(4095 - m);
    sort64_u64(key, lane);
    if (lane < NK) idxo[(b * NN + q0 + j) * NK + lane] = 4095 - (int)(key & 0xFFFFFFFFull);
  }
}

// ---------------- k2: edge-feature moments (6 sums + 21 upper-tri products) ----------------
__global__ __launch_bounds__(256) void k2_mom(const float4* __restrict__ xyzs, const int* __restrict__ idx,
                                              float* __restrict__ part) {
  const int tid = threadIdx.x;
  const int gid = blockIdx.x * 256 + tid;
  float acc[27];
  #pragma unroll
  for (int j = 0; j < 27; ++j) acc[j] = 0.f;
  for (int i = 0; i < 10; ++i) {
    const int s = gid + i * 131072;          // B*N*K = 1310720 = 131072*10
    const int b = s / 163840;                // N*K
    const int r = s - b * 163840;
    const int n = r / 40;
    const int m = idx[s];
    const float4 ct = xyzs[b * NN + n];
    const float4 nb = xyzs[b * NN + m];
    const float e[6] = {nb.x - ct.x, nb.y - ct.y, nb.z - ct.z, ct.x, ct.y, ct.z};
    int t = 6;
    #pragma unroll
    for (int c = 0; c < 6; ++c) {
      acc[c] += e[c];
      #pragma unroll
      for (int d = c; d < 6; ++d) { acc[t] = fmaf(e[c], e[d], acc[t]); ++t; }
    }
  }
  const int w = tid >> 6, lane = tid & 63;
  __shared__ float red[4][27];
  #pragma unroll
  for (int j = 0; j < 27; ++j) {
    float v = acc[j];
    #pragma unroll
    for (int mm = 1; mm < 64; mm <<= 1) v += __shfl_xor(v, mm, 64);
    if (lane == 0) red[w][j] = v;
  }
  __syncthreads();
  if (tid < 27) part[blockIdx.x * 27 + tid] = red[0][tid] + red[1][tid] + red[2][tid] + red[3][tid];
}

// ---------------- k3: BN1 stats (analytic from moments), fold into W1 ----------------
__global__ void k3_stats1(const float* __restrict__ part, const float* __restrict__ W1,
                          const float* __restrict__ g1, const float* __restrict__ b1,
                          float* __restrict__ s1) {
  __shared__ float S[27];
  const int t = threadIdx.x;
  if (t < 27) {
    double s = 0.0;
    for (int p = 0; p < 512; ++p) s += (double)part[p * 27 + t];
    S[t] = (float)s;
  }
  __syncthreads();
  if (t < 64) {
    const float inv = 1.f / 1310720.f;
    float mu[6];
    #pragma unroll
    for (int c = 0; c < 6; ++c) mu[c] = S[c] * inv;
    float M[6][6];
    int tt = 6;
    #pragma unroll
    for (int c = 0; c < 6; ++c) {
      #pragma unroll
      for (int d = c; d < 6; ++d) { const float v = S[tt] * inv; M[c][d] = v; M[d][c] = v; ++tt; }
    }
    float wv[6];
    #pragma unroll
    for (int c = 0; c < 6; ++c) wv[c] = W1[t * 6 + c];
    float mean = 0.f;
    #pragma unroll
    for (int c = 0; c < 6; ++c) mean = fmaf(wv[c], mu[c], mean);
    float e2 = 0.f;
    #pragma unroll
    for (int c = 0; c < 6; ++c) {
      float rowdot = 0.f;
      #pragma unroll
      for (int d = 0; d < 6; ++d) rowdot = fmaf(wv[d], M[c][d], rowdot);
      e2 = fmaf(wv[c], rowdot, e2);
    }
    const float var = e2 - mean * mean;
    const float aa = g1[t] / sqrtf(var + 1e-5f);
    const float cc = b1[t] - mean * aa;
    #pragma unroll
    for (int c = 0; c < 6; ++c) s1[t * 8 + c] = aa * wv[c];  // pre-folded W1' = a1*W1
    s1[t * 8 + 6] = cc;
    s1[t * 8 + 7] = 0.f;
  }
}

// ---------------- k46: W2 stage on MFMA (bf16 16x16x32), tile-pipelined ----------------
// wave = 2 points = 80 samples = 5 column-tiles of 16 (no padding).
// Pipeline: read B-frags(t) -> z-gen(t+1) into other zlds buffer -> MFMA+stats(t).
// z-gen's ~140 independent insts hide the ds_read latency; MFMA+stats (~200 insts)
// drain z-gen(t+1)'s ds_writes before the next iteration reads them.
// C layout (verified m89): col=lane&15, row=(lane>>4)*4+reg. A: row=lane%16,
// k=(lane/16)*8+j. B: col=lane%16, k=(lane/16)*8+j.
// MODE 0: stats + raw-y2 max/min; MODE 1: stats only; MODE 2: final using s2.
template<int MODE>
__global__ __launch_bounds__(256) void k46(const float4* __restrict__ xyzs, const int* __restrict__ idx,
                                           const float* __restrict__ s1, const float* __restrict__ W2,
                                           const float* __restrict__ s2, float* __restrict__ part,
                                           float* __restrict__ ymax, float* __restrict__ ymin,
                                           float* __restrict__ out) {
  __shared__ bf16x8 w2f[8][64];                   // A-fragments [ft*2+kh][lane], 8 KB
  __shared__ unsigned short zlds[4][2][16][64];   // [wave][dbuf][col][g], 16 KB
  __shared__ float red[4][128];                   // 2 KB
  const int tid = threadIdx.x, w = tid >> 6, lane = tid & 63;
  const int G = lane >> 4, l16 = lane & 15;

  // stage W2 -> bf16 A-fragments: chunk = (ftkh, L): value j = W2[ft*16 + L%16][kh*32 + (L/16)*8 + j]
  {
    #pragma unroll
    for (int i = 0; i < 2; ++i) {
      const int chunk = tid * 2 + i;
      const int ftkh = chunk >> 6, L = chunk & 63;
      const int f = (ftkh >> 1) * 16 + (L & 15);
      const int g0 = (ftkh & 1) * 32 + (L >> 4) * 8;
      const float4 wa = *(const float4*)(W2 + f * 64 + g0);
      const float4 wb = *(const float4*)(W2 + f * 64 + g0 + 4);
      bf16x8 v;
      v[0] = (short)f2bf(wa.x); v[1] = (short)f2bf(wa.y);
      v[2] = (short)f2bf(wa.z); v[3] = (short)f2bf(wa.w);
      v[4] = (short)f2bf(wb.x); v[5] = (short)f2bf(wb.y);
      v[6] = (short)f2bf(wb.z); v[7] = (short)f2bf(wb.w);
      w2f[ftkh][L] = v;
    }
  }
  __syncthreads();

  const int pA = blockIdx.x * 8 + w * 2;     // two consecutive points per wave
  const int pB = pA + 1;
  const int pbse = pA & ~(NN - 1);           // b*NN
  // per-lane s1 row (lane = feature g); center term folded into zb (ct dead in loop)
  const float4 s1v0 = ((const float4*)(s1 + lane * 8))[0];   // w0,w1,w2,w3
  const float4 s1v1 = ((const float4*)(s1 + lane * 8))[1];   // w4,w5,cc,pad
  const float s1x = s1v0.x, s1y = s1v0.y, s1z = s1v0.z;
  float zbA, zbB;
  {
    const float4 ctA = xyzs[pA];
    const float4 ctB = xyzs[pB];
    float z = s1v1.z;
    z = fmaf(s1v0.w, ctA.x, z);
    z = fmaf(s1v1.x, ctA.y, z);
    z = fmaf(s1v1.y, ctA.z, z);
    z = fmaf(-s1x, ctA.x, z);
    z = fmaf(-s1y, ctA.y, z);
    z = fmaf(-s1z, ctA.z, z);
    zbA = z;
    z = s1v1.z;
    z = fmaf(s1v0.w, ctB.x, z);
    z = fmaf(s1v1.x, ctB.y, z);
    z = fmaf(s1v1.y, ctB.z, z);
    z = fmaf(-s1x, ctB.x, z);
    z = fmaf(-s1y, ctB.y, z);
    z = fmaf(-s1z, ctB.z, z);
    zbB = z;
  }
  __shared__ float s2l[128];
  if (MODE == 2 && tid < 128) s2l[tid] = s2[tid];
  if (MODE == 2) __syncthreads();

  const int ia0 = (lane < NK) ? idx[pA * NK + lane] : 0;
  const int ia1 = (lane < NK) ? idx[pB * NK + lane] : 0;
  unsigned short* zw = &zlds[w][0][0][0];

  // z-gen for tile TT into buffer BUF (16 independent load->fma->ds_write chains)
  #define K46_ZGEN(TT, BUF)                                             \
  {                                                                     \
    _Pragma("unroll")                                                   \
    for (int c = 0; c < 16; ++c) {                                      \
      const int sidx = (TT) * 16 + c;                                   \
      const int pt = sidx / NK;                                         \
      const int kk = sidx % NK;                                         \
      const int m = __builtin_amdgcn_readlane(pt ? ia1 : ia0, kk);      \
      const float4 nb = xyzs[pbse + m];                                 \
      float z = pt ? zbB : zbA;                                         \
      z = fmaf(s1x, nb.x, z);                                           \
      z = fmaf(s1y, nb.y, z);                                           \
      z = fmaf(s1z, nb.z, z);                                           \
      z = fmaxf(z, 0.2f * z);                                           \
      zw[(BUF) * 1024 + c * 64 + lane] = f2bf(z);                       \
    }                                                                   \
  }

  float s_[4][4], q_[4][4], mx_[4][4], mn_[4][4];
  #pragma unroll
  for (int ft = 0; ft < 4; ++ft)
    #pragma unroll
    for (int r = 0; r < 4; ++r) {
      s_[ft][r] = 0.f; q_[ft][r] = 0.f; mx_[ft][r] = -3.0e38f; mn_[ft][r] = 3.0e38f;
    }

  // prologue: z-gen tile 0 -> buffer 0
  K46_ZGEN(0, 0)

  #pragma unroll
  for (int t = 0; t < 5; ++t) {
    // (1) B-fragments of tile t (written last iteration; drained during its stats)
    const int bo = (t & 1) * 1024;
    const bf16x8 bf0 = *(const bf16x8*)(zw + bo + l16 * 64 + G * 8);
    const bf16x8 bf1 = *(const bf16x8*)(zw + bo + l16 * 64 + 32 + G * 8);
    // (2) z-gen tile t+1 into the other buffer (hides bf read + its own load latency)
    if (t < 4) K46_ZGEN(t + 1, (t + 1) & 1)
    // (3) MFMA + stats of tile t
    #pragma unroll
    for (int ft = 0; ft < 4; ++ft) {
      floatx4 acc = {0.f, 0.f, 0.f, 0.f};
      acc = __builtin_amdgcn_mfma_f32_16x16x32_bf16(w2f[ft * 2 + 0][lane], bf0, acc, 0, 0, 0);
      acc = __builtin_amdgcn_mfma_f32_16x16x32_bf16(w2f[ft * 2 + 1][lane], bf1, acc, 0, 0, 0);
      #pragma unroll
      for (int r = 0; r < 4; ++r) {
        const float y = acc[r];
        if (MODE != 2) { s_[ft][r] += y; q_[ft][r] = fmaf(y, y, q_[ft][r]); }
        float v = y;
        if (MODE == 2) {
          const int fown = ft * 16 + G * 4 + r;   // f of THIS value (row of C)
          const float tv = fmaf(y, s2l[2 * fown], s2l[2 * fown + 1]);
          v = fmaxf(tv, 0.2f * tv);
        }
        if (MODE != 1) {
          if (t == 0 || t == 1 || t == 3) {
            mx_[ft][r] = fmaxf(mx_[ft][r], v);
            if (MODE == 0) mn_[ft][r] = fminf(mn_[ft][r], v);
          } else if (t == 2) {
            // close out point A for this (ft,r): cols 0-7 of this tile belong to A
            float fx = (l16 < 8) ? fmaxf(mx_[ft][r], v) : mx_[ft][r];
            fx = red16max(fx);
            float fn = 3.0e38f;
            if (MODE == 0) {
              fn = (l16 < 8) ? fminf(mn_[ft][r], v) : mn_[ft][r];
              fn = red16min(fn);
            }
            if (l16 == ft * 4 + r) {
              const int f = ft * 16 + G * 4 + r;
              if (MODE == 0) { ymax[pA * NF + f] = fx; ymin[pA * NF + f] = fn; }
              else { out[pbse * NF + f * NN + (pA & (NN - 1))] = fx; }
            }
            mx_[ft][r] = (l16 >= 8) ? v : -3.0e38f;     // start point B
            if (MODE == 0) mn_[ft][r] = (l16 >= 8) ? v : 3.0e38f;
          } else { // t == 4: update + close out point B
            float fx = fmaxf(mx_[ft][r], v);
            fx = red16max(fx);
            float fn = 3.0e38f;
            if (MODE == 0) {
              fn = fminf(mn_[ft][r], v);
              fn = red16min(fn);
            }
            if (l16 == ft * 4 + r) {
              const int f = ft * 16 + G * 4 + r;
              if (MODE == 0) { ymax[pB * NF + f] = fx; ymin[pB * NF + f] = fn; }
              else { out[pbse * NF + f * NN + (pB & (NN - 1))] = fx; }
            }
          }
        }
      }
    }
  }
  #undef K46_ZGEN

  if (MODE != 2) {
    // wave-end: reduce deferred sums over the 16 columns-lanes, owner writes red[w][f]
    #pragma unroll
    for (int ft = 0; ft < 4; ++ft) {
      #pragma unroll
      for (int r = 0; r < 4; ++r) {
        const float ss = red16sum(s_[ft][r]);
        const float qq = red16sum(q_[ft][r]);
        if (l16 == ft * 4 + r) {
          const int f = ft * 16 + G * 4 + r;
          red[w][f] = ss;
          red[w][64 + f] = qq;
        }
      }
    }
    __syncthreads();
    if (tid < 128) part[blockIdx.x * 128 + tid] = red[0][tid] + red[1][tid] + red[2][tid] + red[3][tid];
  }
}

// ---------------- k5a: reduce BN2 partials (4096 x 128) -> sums[128] ----------------
__global__ __launch_bounds__(256) void k5a(const float* __restrict__ part, float* __restrict__ sums) {
  const int t = blockIdx.x;         // stat index 0..127
  const int tid = threadIdx.x;
  double s = 0.0;
  for (int p = tid; p < 4096; p += 256) s += (double)part[p * 128 + t];
  __shared__ double sd[256];
  sd[tid] = s;
  __syncthreads();
  for (int st = 128; st > 0; st >>= 1) {
    if (tid < st) sd[tid] += sd[tid + st];
    __syncthreads();
  }
  if (tid == 0) sums[t] = (float)sd[0];
}

// ---------------- k5b: sums -> affine (a2, c2) ----------------
__global__ void k5b(const float* __restrict__ sums, const float* __restrict__ g2,
                    const float* __restrict__ b2, float* __restrict__ s2) {
  const int t = threadIdx.x;  // 64
  const float inv = 1.f / 1310720.f;
  const float mean = sums[t] * inv;
  const float var = sums[t + 64] * inv - mean * mean;
  const float aa = g2[t] / sqrtf(var + 1e-5f);
  s2[2 * t] = aa;
  s2[2 * t + 1] = b2[t] - mean * aa;
}

// ---------------- k7: affine+lrelu on proper extreme, with LDS tile transpose ----------------
// max_k lrelu(a*y+c) == lrelu(a*max_k y + c) if a>=0 else lrelu(a*min_k y + c)
__global__ __launch_bounds__(256) void k7_apply(const float* __restrict__ ymax, const float* __restrict__ ymin,
                                                const float* __restrict__ s2, float* __restrict__ out) {
  __shared__ float tile[64][65];
  const int blk = blockIdx.x;                 // 0..511
  const int b = blk >> 6, n0 = (blk & 63) * 64;
  const int tid = threadIdx.x;
  const int fr = tid & 63;
  const float aa = s2[2 * fr], cc = s2[2 * fr + 1];
  const bool useMax = (aa >= 0.f);
  #pragma unroll
  for (int it = 0; it < 16; ++it) {
    const int nl = it * 4 + (tid >> 6);
    const int gi = ((b * NN + n0 + nl) << 6) + fr;     // [point][f]
    const float v = useMax ? ymax[gi] : ymin[gi];
    const float t0 = fmaf(aa, v, cc);
    tile[fr][nl] = fmaxf(t0, 0.2f * t0);
  }
  __syncthreads();
  #pragma unroll
  for (int it = 0; it < 16; ++it) {
    const int fw = it * 4 + (tid >> 6);
    const int nl = tid & 63;
    out[(b * NF + fw) * NN + n0 + nl] = tile[fw][nl];  // coalesced
  }
}

extern "C" void kernel_launch(void* const* d_in, const int* in_sizes, int n_in,
                              void* d_out, int out_size, void* d_ws, size_t ws_size,
                              hipStream_t stream) {
  const float* x  = (const float*)d_in[0];
  const float* W1 = (const float*)d_in[1];
  const float* g1 = (const float*)d_in[2];
  const float* b1 = (const float*)d_in[3];
  const float* W2 = (const float*)d_in[4];
  const float* g2 = (const float*)d_in[5];
  const float* b2 = (const float*)d_in[6];
  float* out = (float*)d_out;
  char* ws = (char*)d_ws;
  // workspace layout (16B-aligned slabs)
  float4* xyzs  = (float4*)ws;                       // 524288 B
  int*    idx   = (int*)(ws + 524288);               // 5242880 B -> end 5767168
  float*  part2 = (float*)(ws + 5767168);            // 55296 B   -> end 5822464
  float*  s1    = (float*)(ws + 5822464);            // 2048 B    -> end 5824512
  float*  part4 = (float*)(ws + 5824512);            // 2097152 B -> end 10018816 (slab kept)
  float*  sums  = (float*)(ws + 10018816);           // 512 B     -> end 10019328
  float*  s2    = (float*)(ws + 10019328);           // 512 B     -> end 10019840
  float*  ymax  = (float*)(ws + 10019840);           // 8388608 B -> end 18408448
  float*  ymin  = (float*)(ws + 18408448);           // 8388608 B -> end 26797056
  const size_t FUSED_NEED = 26797056;                // bytes

  k0_prep<<<128, 256, 0, stream>>>(x, xyzs);
  k1_knn<<<512, 1024, 0, stream>>>(xyzs, idx);
  k2_mom<<<512, 256, 0, stream>>>(xyzs, idx, part2);
  k3_stats1<<<1, 64, 0, stream>>>(part2, W1, g1, b1, s1);
  if (ws_size >= FUSED_NEED) {
    k46<0><<<4096, 256, 0, stream>>>(xyzs, idx, s1, W2, s2, part4, ymax, ymin, out);
    k5a<<<128, 256, 0, stream>>>(part4, sums);
    k5b<<<1, 64, 0, stream>>>(sums, g2, b2, s2);
    k7_apply<<<512, 256, 0, stream>>>(ymax, ymin, s2, out);
  } else {
    k46<1><<<4096, 256, 0, stream>>>(xyzs, idx, s1, W2, s2, part4, out, out, out);
    k5a<<<128, 256, 0, stream>>>(part4, sums);
    k5b<<<1, 64, 0, stream>>>(sums, g2, b2, s2);
    k46<2><<<4096, 256, 0, stream>>>(xyzs, idx, s1, W2, s2, part4, out, out, out);
  }
}